// Round 1
// baseline (861.727 us; speedup 1.0000x reference)
//
#include <hip/hip_runtime.h>
#include <hip/hip_bf16.h>

#define M_DIM 8192
#define N_DIM 11008
#define K_DIM 4096

typedef __attribute__((ext_vector_type(8))) short bf16x8;
typedef __attribute__((ext_vector_type(4))) short s16x4;
typedef __attribute__((ext_vector_type(4))) float f32x4;

static __device__ __forceinline__ short f2bf(float f) {
  __hip_bfloat16 h = __float2bfloat16(f);
  return *reinterpret_cast<short*>(&h);
}

// ---------------- per-token quant: n = rint(x/scale), scale = max(absmax,1e-5)/7 ----------------
__global__ void quant_rows_kernel(const float* __restrict__ x,
                                  short* __restrict__ xq,
                                  float* __restrict__ scales) {
  const int row = blockIdx.x;      // 8192 rows
  const int t = threadIdx.x;       // 256 threads
  const float4* xr4 = (const float4*)(x + (size_t)row * K_DIM);
  float4 v[4];
  float amax = 0.0f;
#pragma unroll
  for (int i = 0; i < 4; ++i) {
    v[i] = xr4[t + 256 * i];
    amax = fmaxf(amax, fmaxf(fmaxf(fabsf(v[i].x), fabsf(v[i].y)),
                             fmaxf(fabsf(v[i].z), fabsf(v[i].w))));
  }
#pragma unroll
  for (int off = 32; off > 0; off >>= 1)
    amax = fmaxf(amax, __shfl_xor(amax, off, 64));
  __shared__ float red[4];
  if ((t & 63) == 0) red[t >> 6] = amax;
  __syncthreads();
  amax = fmaxf(fmaxf(red[0], red[1]), fmaxf(red[2], red[3]));
  const float scale = fmaxf(amax, 1e-5f) / 7.0f;   // true div: matches reference bitwise
  if (t == 0) scales[row] = scale;
  s16x4* xq4 = (s16x4*)(xq + (size_t)row * K_DIM);
#pragma unroll
  for (int i = 0; i < 4; ++i) {
    s16x4 q;
    q[0] = f2bf(rintf(v[i].x / scale));  // RNE, int in [-7,7]: exact in bf16
    q[1] = f2bf(rintf(v[i].y / scale));
    q[2] = f2bf(rintf(v[i].z / scale));
    q[3] = f2bf(rintf(v[i].w / scale));
    xq4[t + 256 * i] = q;
  }
}

// ---------------- weight f32 -> bf16 ----------------
__global__ void convw_kernel(const float* __restrict__ w, short* __restrict__ wq) {
  const size_t i = (size_t)blockIdx.x * 256 + threadIdx.x;  // 8 elems each
  const float4 a = ((const float4*)w)[2 * i];
  const float4 b = ((const float4*)w)[2 * i + 1];
  bf16x8 q;
  q[0] = f2bf(a.x); q[1] = f2bf(a.y); q[2] = f2bf(a.z); q[3] = f2bf(a.w);
  q[4] = f2bf(b.x); q[5] = f2bf(b.y); q[6] = f2bf(b.z); q[7] = f2bf(b.w);
  ((bf16x8*)wq)[i] = q;
}

// ---------------- GEMM: out[m][n] = scale[m] * (xq[m,:] . wq[n,:]) + bias[n] ----------------
// m97 structure: 128x128 tile, BK=64, 4 waves (2x2), 4x4 frags of 16x16x32 per wave,
// global_load_lds width=16 staging, single LDS buffer, 2 barriers per K-step.
__global__ __launch_bounds__(256, 2) void gemm_kernel(
    const short* __restrict__ xq, const short* __restrict__ wq,
    const float* __restrict__ scales, const float* __restrict__ bias,
    float* __restrict__ out) {
  __shared__ short As[128][64];
  __shared__ short Bs[128][64];
  const int t = threadIdx.x;
  const int lane = t & 63;
  const int wave = t >> 6;
  const int wr = wave >> 1, wc = wave & 1;
  const int m0 = blockIdx.x * 128;
  const int n0 = blockIdx.y * 128;

  // staging: thread t, round r covers row r*32 + t/8, k-slot (t&7)*8 (16B)
  const int srow = t >> 3;
  const int scol = (t & 7) * 8;
  const short* ag = xq + (size_t)(m0 + srow) * K_DIM + scol;
  const short* bg = wq + (size_t)(n0 + srow) * K_DIM + scol;
  char* asb = (char*)&As[0][0] + wave * 1024;  // wave-uniform LDS base; HW adds lane*16
  char* bsb = (char*)&Bs[0][0] + wave * 1024;

  f32x4 acc[4][4] = {};

  for (int kt = 0; kt < K_DIM; kt += 64) {
#pragma unroll
    for (int r = 0; r < 4; ++r) {
      __builtin_amdgcn_global_load_lds(
          (const __attribute__((address_space(1))) void*)(ag + (size_t)r * 32 * K_DIM + kt),
          (__attribute__((address_space(3))) void*)(asb + r * 4096), 16, 0, 0);
      __builtin_amdgcn_global_load_lds(
          (const __attribute__((address_space(1))) void*)(bg + (size_t)r * 32 * K_DIM + kt),
          (__attribute__((address_space(3))) void*)(bsb + r * 4096), 16, 0, 0);
    }
    asm volatile("s_waitcnt vmcnt(0)" ::: "memory");
    __syncthreads();
#pragma unroll
    for (int kk = 0; kk < 64; kk += 32) {
      const int kb = kk + (lane >> 4) * 8;
      bf16x8 a[4], b[4];
#pragma unroll
      for (int m = 0; m < 4; ++m)
        a[m] = *(const bf16x8*)&As[wr * 64 + m * 16 + (lane & 15)][kb];
#pragma unroll
      for (int n = 0; n < 4; ++n)
        b[n] = *(const bf16x8*)&Bs[wc * 64 + n * 16 + (lane & 15)][kb];
#pragma unroll
      for (int m = 0; m < 4; ++m)
#pragma unroll
        for (int n = 0; n < 4; ++n)
          acc[m][n] = __builtin_amdgcn_mfma_f32_16x16x32_bf16(a[m], b[n], acc[m][n], 0, 0, 0);
    }
    __syncthreads();
  }

  // C/D layout (m89/m91 verified): col = lane&15, row = (lane>>4)*4 + reg
  const int crow = wr * 64 + ((lane >> 4) << 2);
  const int ccol = wc * 64 + (lane & 15);
#pragma unroll
  for (int m = 0; m < 4; ++m) {
#pragma unroll
    for (int j = 0; j < 4; ++j) {
      const int grow = m0 + crow + m * 16 + j;
      const float s = scales[grow];
      float* orow = out + (size_t)grow * N_DIM + n0 + ccol;
#pragma unroll
      for (int n = 0; n < 4; ++n)
        orow[n * 16] = acc[m][n][j] * s + bias[n0 + ccol + n * 16];
    }
  }
}

extern "C" void kernel_launch(void* const* d_in, const int* in_sizes, int n_in,
                              void* d_out, int out_size, void* d_ws, size_t ws_size,
                              hipStream_t stream) {
  (void)in_sizes; (void)n_in; (void)out_size; (void)ws_size;
  const float* x = (const float*)d_in[0];       // [4,2048,4096] f32
  const float* w = (const float*)d_in[1];       // [11008,4096] f32
  const float* bias = (const float*)d_in[2];    // [1,11008] f32
  float* out = (float*)d_out;                   // [8192,11008] f32

  char* ws = (char*)d_ws;
  float* scales = (float*)ws;                                   // 32 KiB
  short* xq = (short*)(ws + (1 << 15));                         // 64 MiB bf16
  short* wq = (short*)(ws + (1 << 15) + (size_t)M_DIM * K_DIM * 2);  // 86 MiB bf16

  quant_rows_kernel<<<M_DIM, 256, 0, stream>>>(x, xq, scales);
  convw_kernel<<<(int)(((size_t)N_DIM * K_DIM) / 8 / 256), 256, 0, stream>>>(w, wq);
  dim3 grid(M_DIM / 128, N_DIM / 128);  // 64 x 86
  gemm_kernel<<<grid, 256, 0, stream>>>(xq, wq, scales, bias, out);
}

// Round 2
// 818.817 us; speedup vs baseline: 1.0524x; 1.0524x over previous
//
#include <hip/hip_runtime.h>
#include <hip/hip_bf16.h>

#define M_DIM 8192
#define N_DIM 11008
#define K_DIM 4096
#define NT 128            // K-tiles of BK=32
#define LDS_SLOT 16384    // bytes per operand slot: 256 rows x 32 k x 2B
#define LDS_B_OFF 65536   // B region starts at 64 KiB

typedef __attribute__((ext_vector_type(8))) short bf16x8;
typedef __attribute__((ext_vector_type(4))) short s16x4;
typedef __attribute__((ext_vector_type(4))) float f32x4;

static __device__ __forceinline__ short f2bf(float f) {
  __hip_bfloat16 h = __float2bfloat16(f);
  return *reinterpret_cast<short*>(&h);
}

// ---------------- per-token quant: n = rint(x/scale), scale = max(absmax,1e-5)/7 ----------------
__global__ void quant_rows_kernel(const float* __restrict__ x,
                                  short* __restrict__ xq,
                                  float* __restrict__ scales) {
  const int row = blockIdx.x;      // 8192 rows
  const int t = threadIdx.x;       // 256 threads
  const float4* xr4 = (const float4*)(x + (size_t)row * K_DIM);
  float4 v[4];
  float amax = 0.0f;
#pragma unroll
  for (int i = 0; i < 4; ++i) {
    v[i] = xr4[t + 256 * i];
    amax = fmaxf(amax, fmaxf(fmaxf(fabsf(v[i].x), fabsf(v[i].y)),
                             fmaxf(fabsf(v[i].z), fabsf(v[i].w))));
  }
#pragma unroll
  for (int off = 32; off > 0; off >>= 1)
    amax = fmaxf(amax, __shfl_xor(amax, off, 64));
  __shared__ float red[4];
  if ((t & 63) == 0) red[t >> 6] = amax;
  __syncthreads();
  amax = fmaxf(fmaxf(red[0], red[1]), fmaxf(red[2], red[3]));
  const float scale = fmaxf(amax, 1e-5f) / 7.0f;   // true div: matches reference
  if (t == 0) scales[row] = scale;
  s16x4* xq4 = (s16x4*)(xq + (size_t)row * K_DIM);
#pragma unroll
  for (int i = 0; i < 4; ++i) {
    s16x4 q;
    q[0] = f2bf(rintf(v[i].x / scale));  // RNE int in [-7,7]: exact in bf16
    q[1] = f2bf(rintf(v[i].y / scale));
    q[2] = f2bf(rintf(v[i].z / scale));
    q[3] = f2bf(rintf(v[i].w / scale));
    xq4[t + 256 * i] = q;
  }
}

// ---------------- weight f32 -> bf16 ----------------
__global__ void convw_kernel(const float* __restrict__ w, short* __restrict__ wq) {
  const size_t i = (size_t)blockIdx.x * 256 + threadIdx.x;  // 8 elems each
  const float4 a = ((const float4*)w)[2 * i];
  const float4 b = ((const float4*)w)[2 * i + 1];
  bf16x8 q;
  q[0] = f2bf(a.x); q[1] = f2bf(a.y); q[2] = f2bf(a.z); q[3] = f2bf(a.w);
  q[4] = f2bf(b.x); q[5] = f2bf(b.y); q[6] = f2bf(b.z); q[7] = f2bf(b.w);
  ((bf16x8*)wq)[i] = q;
}

// ---------------- staging: linear LDS dest, inverse-swizzled global source ----------------
// LDS logical layout per slot: [256 rows][32 k] bf16, row stride 64 B.
// Swizzle: phys_byte = row*64 + (colbyte ^ ((row&3)<<4)).
__device__ __forceinline__ void stage_a(const short* gA, char* sdA, int u) {
  const int s = (u & 3) * LDS_SLOT;
  const short* g = gA + (size_t)u * 32;
  __builtin_amdgcn_global_load_lds((const __attribute__((address_space(1))) void*)g,
      (__attribute__((address_space(3))) void*)(sdA + s), 16, 0, 0);
  __builtin_amdgcn_global_load_lds((const __attribute__((address_space(1))) void*)(g + (size_t)128 * K_DIM),
      (__attribute__((address_space(3))) void*)(sdA + s + 8192), 16, 0, 0);
}
__device__ __forceinline__ void stage_b(const short* gB, char* sdB, int u) {
  const int s = (u & 3) * LDS_SLOT;
  const short* g = gB + (size_t)u * 32;
  __builtin_amdgcn_global_load_lds((const __attribute__((address_space(1))) void*)g,
      (__attribute__((address_space(3))) void*)(sdB + s), 16, 0, 0);
  __builtin_amdgcn_global_load_lds((const __attribute__((address_space(1))) void*)(g + (size_t)128 * K_DIM),
      (__attribute__((address_space(3))) void*)(sdB + s + 8192), 16, 0, 0);
}

// One K-tile (BK=32): 2 phases, 32 MFMA/wave, counted vmcnt at tile end.
template<bool STG, int VMC>
__device__ __forceinline__ void tile_body(int t, char* lds_c, int aBase, int bBase,
    const short* gA, const short* gB, char* sdA, char* sdB, f32x4 (&acc)[8][4]) {
  const int slot = (t & 3) * LDS_SLOT;
  const char* pa = lds_c + slot + aBase;
  const char* pb = lds_c + LDS_B_OFF + slot + bBase;
  bf16x8 af[4], bf[4];
  // ---- phase 1: A frag-rows 0-3 + all B frag-cols; stage A(t+3) ----
#pragma unroll
  for (int i = 0; i < 4; ++i) af[i] = *(const bf16x8*)(pa + i * 1024);
#pragma unroll
  for (int i = 0; i < 4; ++i) bf[i] = *(const bf16x8*)(pb + i * 1024);
  if constexpr (STG) stage_a(gA, sdA, t + 3);
  asm volatile("s_barrier" ::: "memory");
  __builtin_amdgcn_sched_barrier(0);
  __builtin_amdgcn_s_setprio(1);
#pragma unroll
  for (int m = 0; m < 4; ++m)
#pragma unroll
    for (int n = 0; n < 4; ++n)
      acc[m][n] = __builtin_amdgcn_mfma_f32_16x16x32_bf16(af[m], bf[n], acc[m][n], 0, 0, 0);
  __builtin_amdgcn_s_setprio(0);
  __builtin_amdgcn_sched_barrier(0);
  asm volatile("s_barrier" ::: "memory");
  // ---- phase 2: A frag-rows 4-7 (reuse B); stage B(t+3) ----
#pragma unroll
  for (int i = 0; i < 4; ++i) af[i] = *(const bf16x8*)(pa + 4096 + i * 1024);
  if constexpr (STG) stage_b(gB, sdB, t + 3);
  asm volatile("s_barrier" ::: "memory");
  __builtin_amdgcn_sched_barrier(0);
  __builtin_amdgcn_s_setprio(1);
#pragma unroll
  for (int m = 0; m < 4; ++m)
#pragma unroll
    for (int n = 0; n < 4; ++n)
      acc[4 + m][n] = __builtin_amdgcn_mfma_f32_16x16x32_bf16(af[m], bf[n], acc[4 + m][n], 0, 0, 0);
  __builtin_amdgcn_s_setprio(0);
  __builtin_amdgcn_sched_barrier(0);
  if constexpr (VMC == 8)      asm volatile("s_waitcnt vmcnt(8)" ::: "memory");
  else if constexpr (VMC == 4) asm volatile("s_waitcnt vmcnt(4)" ::: "memory");
  else if constexpr (VMC == 0) asm volatile("s_waitcnt vmcnt(0)" ::: "memory");
  asm volatile("s_barrier" ::: "memory");
}

// ---------------- GEMM: 256x256 tile, BK=32, ring-4 LDS, counted-vmcnt phase schedule ----------------
__global__ __launch_bounds__(512, 2) void gemm_kernel(
    const short* __restrict__ xq, const short* __restrict__ wq,
    const float* __restrict__ scales, const float* __restrict__ bias,
    float* __restrict__ out) {
  __shared__ short lds[65536];  // 128 KiB: A slots [0,64K), B slots [64K,128K)
  char* lds_c = (char*)lds;

  const int tid = threadIdx.x;
  const int lane = tid & 63;
  const int wave = tid >> 6;      // 0..7
  const int wm = wave >> 2;       // 0..1 -> 128-row half
  const int wn = wave & 3;        // 0..3 -> 64-col slice

  // T1: bijective XCD swizzle (1376 = 8*172 exactly)
  const int bid = blockIdx.x;
  const int sw = (bid & 7) * 172 + (bid >> 3);
  const int bm = sw / 43, bn = sw % 43;
  const int m0 = bm * 256, n0 = bn * 256;

  // staging source (inverse swizzle baked into global column)
  const int srow = tid >> 2;                                 // 0..127
  const int scolb = ((tid & 3) << 4) ^ ((srow & 3) << 4);    // logical colbyte
  const short* gA = xq + (size_t)(m0 + srow) * K_DIM + (scolb >> 1);
  const short* gB = wq + (size_t)(n0 + srow) * K_DIM + (scolb >> 1);
  char* sdA = lds_c + wave * 1024;              // wave-uniform; HW adds lane*16
  char* sdB = lds_c + LDS_B_OFF + wave * 1024;

  // fragment read bases (swizzled)
  const int lr = lane & 15;
  const int xorterm = ((lane >> 4) << 4) ^ ((lr & 3) << 4);
  const int aBase = (wm * 128 + lr) * 64 + xorterm;
  const int bBase = (wn * 64 + lr) * 64 + xorterm;

  f32x4 acc[8][4] = {};

  // prologue: stage tiles 0,1,2 (12 loads); wait oldest 4 (tile 0) landed
  stage_a(gA, sdA, 0); stage_b(gB, sdB, 0);
  stage_a(gA, sdA, 1); stage_b(gB, sdB, 1);
  stage_a(gA, sdA, 2); stage_b(gB, sdB, 2);
  asm volatile("s_waitcnt vmcnt(8)" ::: "memory");
  asm volatile("s_barrier" ::: "memory");

  for (int t = 0; t < NT - 3; ++t)
    tile_body<true, 8>(t, lds_c, aBase, bBase, gA, gB, sdA, sdB, acc);
  tile_body<false, 4>(NT - 3, lds_c, aBase, bBase, gA, gB, sdA, sdB, acc);
  tile_body<false, 0>(NT - 2, lds_c, aBase, bBase, gA, gB, sdA, sdB, acc);
  tile_body<false, -1>(NT - 1, lds_c, aBase, bBase, gA, gB, sdA, sdB, acc);

  // epilogue: C/D layout col=lane&15, row=(lane>>4)*4+reg (m89/m91)
  const int orow0 = m0 + wm * 128 + (lane >> 4) * 4;
  const int ocol0 = n0 + wn * 64 + lr;
  float bv[4];
#pragma unroll
  for (int fc = 0; fc < 4; ++fc) bv[fc] = bias[ocol0 + fc * 16];
#pragma unroll
  for (int fr = 0; fr < 8; ++fr) {
#pragma unroll
    for (int j = 0; j < 4; ++j) {
      const int grow = orow0 + fr * 16 + j;
      const float s = scales[grow];
      float* op = out + (size_t)grow * N_DIM + ocol0;
#pragma unroll
      for (int fc = 0; fc < 4; ++fc)
        op[fc * 16] = acc[fr][fc][j] * s + bv[fc];
    }
  }
}

extern "C" void kernel_launch(void* const* d_in, const int* in_sizes, int n_in,
                              void* d_out, int out_size, void* d_ws, size_t ws_size,
                              hipStream_t stream) {
  (void)in_sizes; (void)n_in; (void)out_size; (void)ws_size;
  const float* x = (const float*)d_in[0];       // [4,2048,4096] f32
  const float* w = (const float*)d_in[1];       // [11008,4096] f32
  const float* bias = (const float*)d_in[2];    // [1,11008] f32
  float* out = (float*)d_out;                   // [8192,11008] f32

  char* ws = (char*)d_ws;
  float* scales = (float*)ws;                                        // 32 KiB
  short* xq = (short*)(ws + (1 << 15));                              // 64 MiB bf16
  short* wq = (short*)(ws + (1 << 15) + (size_t)M_DIM * K_DIM * 2);  // 86 MiB bf16

  quant_rows_kernel<<<M_DIM, 256, 0, stream>>>(x, xq, scales);
  convw_kernel<<<(int)(((size_t)N_DIM * K_DIM) / 8 / 256), 256, 0, stream>>>(w, wq);
  gemm_kernel<<<dim3((M_DIM / 256) * (N_DIM / 256)), 512, 0, stream>>>(xq, wq, scales, bias, out);
}

// Round 3
// 738.509 us; speedup vs baseline: 1.1668x; 1.1087x over previous
//
#include <hip/hip_runtime.h>
#include <hip/hip_bf16.h>

#define M_DIM 8192
#define N_DIM 11008
#define K_DIM 4096
#define NT64 64           // K-tiles of BK=64
#define ROW64K ((size_t)64 * K_DIM)

typedef __attribute__((ext_vector_type(8))) short bf16x8;
typedef __attribute__((ext_vector_type(4))) short s16x4;
typedef __attribute__((ext_vector_type(4))) float f32x4;

static __device__ __forceinline__ short f2bf(float f) {
  __hip_bfloat16 h = __float2bfloat16(f);
  return *reinterpret_cast<short*>(&h);
}

// ---------------- per-token quant: n = rint(x/scale), scale = max(absmax,1e-5)/7 ----------------
__global__ void quant_rows_kernel(const float* __restrict__ x,
                                  short* __restrict__ xq,
                                  float* __restrict__ scales) {
  const int row = blockIdx.x;
  const int t = threadIdx.x;
  const float4* xr4 = (const float4*)(x + (size_t)row * K_DIM);
  float4 v[4];
  float amax = 0.0f;
#pragma unroll
  for (int i = 0; i < 4; ++i) {
    v[i] = xr4[t + 256 * i];
    amax = fmaxf(amax, fmaxf(fmaxf(fabsf(v[i].x), fabsf(v[i].y)),
                             fmaxf(fabsf(v[i].z), fabsf(v[i].w))));
  }
#pragma unroll
  for (int off = 32; off > 0; off >>= 1)
    amax = fmaxf(amax, __shfl_xor(amax, off, 64));
  __shared__ float red[4];
  if ((t & 63) == 0) red[t >> 6] = amax;
  __syncthreads();
  amax = fmaxf(fmaxf(red[0], red[1]), fmaxf(red[2], red[3]));
  const float scale = fmaxf(amax, 1e-5f) / 7.0f;
  if (t == 0) scales[row] = scale;
  s16x4* xq4 = (s16x4*)(xq + (size_t)row * K_DIM);
#pragma unroll
  for (int i = 0; i < 4; ++i) {
    s16x4 q;
    q[0] = f2bf(rintf(v[i].x / scale));
    q[1] = f2bf(rintf(v[i].y / scale));
    q[2] = f2bf(rintf(v[i].z / scale));
    q[3] = f2bf(rintf(v[i].w / scale));
    xq4[t + 256 * i] = q;
  }
}

// ---------------- weight f32 -> bf16 ----------------
__global__ void convw_kernel(const float* __restrict__ w, short* __restrict__ wq) {
  const size_t i = (size_t)blockIdx.x * 256 + threadIdx.x;
  const float4 a = ((const float4*)w)[2 * i];
  const float4 b = ((const float4*)w)[2 * i + 1];
  bf16x8 q;
  q[0] = f2bf(a.x); q[1] = f2bf(a.y); q[2] = f2bf(a.z); q[3] = f2bf(a.w);
  q[4] = f2bf(b.x); q[5] = f2bf(b.y); q[6] = f2bf(b.z); q[7] = f2bf(b.w);
  ((bf16x8*)wq)[i] = q;
}

// ---------------- GEMM ----------------
// 256x256 tile, BK=64, 512 thr (8 waves 2x4), ring-2 LDS 128 KiB, 4 phases/tile.
// LDS swizzle: phys = row*128 + (colbyte ^ ((row&7)<<4)); staged via inverse-swizzled
// global source (linear gload_lds dest), read with swizzled col. (G4 / rule #21)
#define GL(g, d)                                                             \
  __builtin_amdgcn_global_load_lds(                                          \
      (const __attribute__((address_space(1))) void*)(g),                    \
      (__attribute__((address_space(3))) void*)(d), 16, 0, 0)

// One phase: ds_read af (+bf if RB) || stage 2 regions -> barrier -> 16 MFMA -> vmcnt -> barrier
template<int MH, int KS, bool RB, int SOP, int VMC, bool STG>
__device__ __forceinline__ void phase(const char* paRow, const char* pbRow, int colswz,
    const short* gAn, const short* gBn, char* dA, char* dB,
    f32x4 (&acc)[8][4], bf16x8 (&bf)[4]) {
  const int col = colswz ^ (KS * 64);
  bf16x8 af[4];
#pragma unroll
  for (int i = 0; i < 4; ++i)
    af[i] = *(const bf16x8*)(paRow + MH * 8192 + i * 2048 + col);
  if constexpr (RB) {
#pragma unroll
    for (int i = 0; i < 4; ++i)
      bf[i] = *(const bf16x8*)(pbRow + i * 2048 + col);
  }
  if constexpr (STG) {
    if constexpr (SOP == 0) { GL(gAn,              dA);          GL(gAn + 2 * ROW64K, dA + 16384); }
    else if constexpr (SOP == 1) { GL(gBn,          dB);          GL(gBn + ROW64K,     dB + 8192); }
    else if constexpr (SOP == 2) { GL(gBn + 2 * ROW64K, dB + 16384); GL(gBn + 3 * ROW64K, dB + 24576); }
    else                  { GL(gAn + ROW64K,     dA + 8192);   GL(gAn + 3 * ROW64K, dA + 24576); }
  }
  asm volatile("s_barrier" ::: "memory");
  __builtin_amdgcn_sched_barrier(0);
  __builtin_amdgcn_s_setprio(1);
#pragma unroll
  for (int m = 0; m < 4; ++m)
#pragma unroll
    for (int n = 0; n < 4; ++n)
      acc[MH * 4 + m][n] = __builtin_amdgcn_mfma_f32_16x16x32_bf16(af[m], bf[n], acc[MH * 4 + m][n], 0, 0, 0);
  __builtin_amdgcn_s_setprio(0);
  __builtin_amdgcn_sched_barrier(0);
  if constexpr (VMC == 2) asm volatile("s_waitcnt vmcnt(2)" ::: "memory");
  if constexpr (VMC == 0) asm volatile("s_waitcnt vmcnt(0)" ::: "memory");
  if constexpr (VMC >= 0) asm volatile("s_barrier" ::: "memory");
  else asm volatile("s_barrier" ::: "memory");
}

__global__ __launch_bounds__(512, 2) void gemm_kernel(
    const short* __restrict__ xq, const short* __restrict__ wq,
    const float* __restrict__ scales, const float* __restrict__ bias,
    float* __restrict__ out) {
  __shared__ short lds[65536];  // A: [0,64K) bufs 0/1; B: [64K,128K) bufs 0/1
  char* lds_c = (char*)lds;

  const int tid = threadIdx.x;
  const int lane = tid & 63;
  const int wave = tid >> 6;
  const int wm = wave >> 2;       // 0..1
  const int wn = wave & 3;        // 0..3
  const int lr = lane & 15;

  // T1: bijective XCD swizzle (1376 = 8*172)
  const int bid = blockIdx.x;
  const int sw = (bid & 7) * 172 + (bid >> 3);
  const int bm = sw / 43, bn = sw % 43;
  const int m0 = bm * 256, n0 = bn * 256;

  // staging source: thread t -> row tid>>3 (0..63), phys colbyte (tid&7)*16,
  // source colbyte = phys ^ ((row&7)<<4)  (inverse swizzle)
  const int srow = tid >> 3;
  const int srccb = ((tid & 7) << 4) ^ ((srow & 7) << 4);
  const short* gA0 = xq + (size_t)(m0 + srow) * K_DIM + (srccb >> 1);
  const short* gB0 = wq + (size_t)(n0 + srow) * K_DIM + (srccb >> 1);
  char* dA0 = lds_c + wave * 1024;            // wave-uniform; HW adds lane*16
  char* dB0 = lds_c + 65536 + wave * 1024;

  // read-side bases
  const int aRowOff = (wm * 128 + lr) * 128;
  const int bRowOff = (wn * 64 + lr) * 128;
  const int colswz = ((lane >> 4) << 4) ^ ((lr & 7) << 4);

  f32x4 acc[8][4] = {};

  // prologue: stage tile 0 in region order a0,a2,b0,b1,b2,b3,a1,a3
  GL(gA0, dA0); GL(gA0 + 2 * ROW64K, dA0 + 16384);
  GL(gB0, dB0); GL(gB0 + ROW64K, dB0 + 8192);
  GL(gB0 + 2 * ROW64K, dB0 + 16384); GL(gB0 + 3 * ROW64K, dB0 + 24576);
  GL(gA0 + ROW64K, dA0 + 8192); GL(gA0 + 3 * ROW64K, dA0 + 24576);
  asm volatile("s_waitcnt vmcnt(2)" ::: "memory");
  asm volatile("s_barrier" ::: "memory");

  for (int t = 0; t < NT64 - 1; ++t) {
    const int buf = t & 1;
    const char* paRow = lds_c + buf * 32768 + aRowOff;
    const char* pbRow = lds_c + 65536 + buf * 32768 + bRowOff;
    const short* gAn = gA0 + (size_t)(t + 1) * 64;
    const short* gBn = gB0 + (size_t)(t + 1) * 64;
    char* dA = dA0 + (1 - buf) * 32768;
    char* dB = dB0 + (1 - buf) * 32768;
    bf16x8 bf[4];
    phase<0, 0, true,  0,  2, true>(paRow, pbRow, colswz, gAn, gBn, dA, dB, acc, bf);
    phase<1, 0, false, 1, -1, true>(paRow, pbRow, colswz, gAn, gBn, dA, dB, acc, bf);
    phase<0, 1, true,  2, -1, true>(paRow, pbRow, colswz, gAn, gBn, dA, dB, acc, bf);
    phase<1, 1, false, 3,  2, true>(paRow, pbRow, colswz, gAn, gBn, dA, dB, acc, bf);
  }
  {  // tail tile (no staging; drain a1,a3 at ph1-end)
    const int buf = (NT64 - 1) & 1;
    const char* paRow = lds_c + buf * 32768 + aRowOff;
    const char* pbRow = lds_c + 65536 + buf * 32768 + bRowOff;
    bf16x8 bf[4];
    phase<0, 0, true,  0,  0, false>(paRow, pbRow, colswz, nullptr, nullptr, nullptr, nullptr, acc, bf);
    phase<1, 0, false, 1, -1, false>(paRow, pbRow, colswz, nullptr, nullptr, nullptr, nullptr, acc, bf);
    phase<0, 1, true,  2, -1, false>(paRow, pbRow, colswz, nullptr, nullptr, nullptr, nullptr, acc, bf);
    phase<1, 1, false, 3, -1, false>(paRow, pbRow, colswz, nullptr, nullptr, nullptr, nullptr, acc, bf);
  }

  // epilogue: C/D layout col=lane&15, row=(lane>>4)*4+reg (m89/m91)
  const int orow0 = m0 + wm * 128 + (lane >> 4) * 4;
  const int ocol0 = n0 + wn * 64 + lr;
  float bv[4];
#pragma unroll
  for (int fc = 0; fc < 4; ++fc) bv[fc] = bias[ocol0 + fc * 16];
#pragma unroll
  for (int fr = 0; fr < 8; ++fr) {
#pragma unroll
    for (int j = 0; j < 4; ++j) {
      const int grow = orow0 + fr * 16 + j;
      const float s = scales[grow];
      float* op = out + (size_t)grow * N_DIM + ocol0;
#pragma unroll
      for (int fc = 0; fc < 4; ++fc)
        op[fc * 16] = acc[fr][fc][j] * s + bv[fc];
    }
  }
}

extern "C" void kernel_launch(void* const* d_in, const int* in_sizes, int n_in,
                              void* d_out, int out_size, void* d_ws, size_t ws_size,
                              hipStream_t stream) {
  (void)in_sizes; (void)n_in; (void)out_size; (void)ws_size;
  const float* x = (const float*)d_in[0];
  const float* w = (const float*)d_in[1];
  const float* bias = (const float*)d_in[2];
  float* out = (float*)d_out;

  char* ws = (char*)d_ws;
  float* scales = (float*)ws;
  short* xq = (short*)(ws + (1 << 15));
  short* wq = (short*)(ws + (1 << 15) + (size_t)M_DIM * K_DIM * 2);

  quant_rows_kernel<<<M_DIM, 256, 0, stream>>>(x, xq, scales);
  convw_kernel<<<(int)(((size_t)N_DIM * K_DIM) / 8 / 256), 256, 0, stream>>>(w, wq);
  gemm_kernel<<<dim3((M_DIM / 256) * (N_DIM / 256)), 512, 0, stream>>>(xq, wq, scales, bias, out);
}

// Round 4
// 482.380 us; speedup vs baseline: 1.7864x; 1.5310x over previous
//
#include <hip/hip_runtime.h>
#include <hip/hip_bf16.h>

#define M_DIM 8192
#define N_DIM 11008
#define K_DIM 4096
#define NT 32                        // K-tiles of BK=128 (int8)
#define RROW ((size_t)64 * K_DIM)    // 64 rows of int8, in bytes

typedef __attribute__((ext_vector_type(4))) int i32x4;

// ---------------- per-token activation quant: n = rint(x/s), s = max(absmax,1e-5)/7 ----------------
__global__ void quant_x_kernel(const float* __restrict__ x,
                               char* __restrict__ xq, float* __restrict__ sx) {
  const int row = blockIdx.x;      // 8192
  const int t = threadIdx.x;       // 256
  const float4* xr4 = (const float4*)(x + (size_t)row * K_DIM);
  float4 v[4];
  float amax = 0.0f;
#pragma unroll
  for (int i = 0; i < 4; ++i) {
    v[i] = xr4[t + 256 * i];
    amax = fmaxf(amax, fmaxf(fmaxf(fabsf(v[i].x), fabsf(v[i].y)),
                             fmaxf(fabsf(v[i].z), fabsf(v[i].w))));
  }
#pragma unroll
  for (int off = 32; off > 0; off >>= 1)
    amax = fmaxf(amax, __shfl_xor(amax, off, 64));
  __shared__ float red[4];
  if ((t & 63) == 0) red[t >> 6] = amax;
  __syncthreads();
  amax = fmaxf(fmaxf(red[0], red[1]), fmaxf(red[2], red[3]));
  const float s = fmaxf(amax, 1e-5f) / 7.0f;   // matches reference bitwise
  if (t == 0) sx[row] = s;
  char q[16];
#pragma unroll
  for (int i = 0; i < 4; ++i) {
    q[i * 4 + 0] = (char)(int)rintf(v[i].x / s);  // RNE, exact ints in [-7,7]
    q[i * 4 + 1] = (char)(int)rintf(v[i].y / s);
    q[i * 4 + 2] = (char)(int)rintf(v[i].z / s);
    q[i * 4 + 3] = (char)(int)rintf(v[i].w / s);
  }
  *(int4*)(xq + (size_t)row * K_DIM + t * 16) = *(int4*)q;
}

// ---------------- per-output-channel weight quant: int8 / 127 ----------------
__global__ void quant_w_kernel(const float* __restrict__ w,
                               char* __restrict__ wq, float* __restrict__ sw) {
  const int row = blockIdx.x;      // 11008
  const int t = threadIdx.x;       // 256
  const float4* wr4 = (const float4*)(w + (size_t)row * K_DIM);
  float4 v[4];
  float amax = 0.0f;
#pragma unroll
  for (int i = 0; i < 4; ++i) {
    v[i] = wr4[t + 256 * i];
    amax = fmaxf(amax, fmaxf(fmaxf(fabsf(v[i].x), fabsf(v[i].y)),
                             fmaxf(fabsf(v[i].z), fabsf(v[i].w))));
  }
#pragma unroll
  for (int off = 32; off > 0; off >>= 1)
    amax = fmaxf(amax, __shfl_xor(amax, off, 64));
  __shared__ float red[4];
  if ((t & 63) == 0) red[t >> 6] = amax;
  __syncthreads();
  amax = fmaxf(fmaxf(red[0], red[1]), fmaxf(red[2], red[3]));
  const float s = fmaxf(amax, 1e-30f) / 127.0f;
  if (t == 0) sw[row] = s;
  char q[16];
#pragma unroll
  for (int i = 0; i < 4; ++i) {
    q[i * 4 + 0] = (char)(int)rintf(v[i].x / s);  // in [-127,127]
    q[i * 4 + 1] = (char)(int)rintf(v[i].y / s);
    q[i * 4 + 2] = (char)(int)rintf(v[i].z / s);
    q[i * 4 + 3] = (char)(int)rintf(v[i].w / s);
  }
  *(int4*)(wq + (size_t)row * K_DIM + t * 16) = *(int4*)q;
}

// ---------------- GEMM ----------------
// 256x256 tile, BK=128 int8 (128-B rows), 512 thr (8 waves 2x4), ring-2 LDS 128 KiB.
// 4 phases/tile; ALL 8 stage loads of tile t+1 issued at phase 1 of tile t
// (target buffer free since end of t-1). vmcnt(8) at ph1-end (drain this tile's
// a1,a3, issued one tile earlier), vmcnt(2) at ph4-end (drain t+1's first-6,
// issued 3 phases earlier). Never 0 in the main loop.
// Swizzle (byte-identical to R3, measured 0 conflicts): phys = row*128 + (col ^ ((row&7)<<4)),
// staged via inverse-swizzled global source (linear gload_lds dest).
#define GL(g, d)                                                             \
  __builtin_amdgcn_global_load_lds(                                          \
      (const __attribute__((address_space(1))) void*)(g),                    \
      (__attribute__((address_space(3))) void*)(d), 16, 0, 0)

template<int MH, int KS, bool RB, int VMC, bool STG>
__device__ __forceinline__ void phase(const char* paRow, const char* pbRow, int colswz,
    const char* gAn, const char* gBn, char* dA, char* dB,
    i32x4 (&acc)[8][4], i32x4 (&bf)[4]) {
  const int col = colswz ^ (KS * 64);
  i32x4 af[4];
#pragma unroll
  for (int i = 0; i < 4; ++i)
    af[i] = *(const i32x4*)(paRow + MH * 8192 + i * 2048 + col);
  if constexpr (RB) {
#pragma unroll
    for (int i = 0; i < 4; ++i)
      bf[i] = *(const i32x4*)(pbRow + i * 2048 + col);
  }
  if constexpr (STG) {
    // first-6 (needed at next tile ph1), then a1,a3 (needed at next tile ph2)
    GL(gAn, dA);                    GL(gAn + 2 * RROW, dA + 16384);
    GL(gBn, dB);                    GL(gBn + RROW, dB + 8192);
    GL(gBn + 2 * RROW, dB + 16384); GL(gBn + 3 * RROW, dB + 24576);
    GL(gAn + RROW, dA + 8192);      GL(gAn + 3 * RROW, dA + 24576);
  }
  asm volatile("s_barrier" ::: "memory");
  __builtin_amdgcn_sched_barrier(0);
  __builtin_amdgcn_s_setprio(1);
#pragma unroll
  for (int m = 0; m < 4; ++m)
#pragma unroll
    for (int n = 0; n < 4; ++n)
      acc[MH * 4 + m][n] = __builtin_amdgcn_mfma_i32_16x16x64_i8(af[m], bf[n], acc[MH * 4 + m][n], 0, 0, 0);
  __builtin_amdgcn_s_setprio(0);
  __builtin_amdgcn_sched_barrier(0);
  if constexpr (VMC == 8) asm volatile("s_waitcnt vmcnt(8)" ::: "memory");
  if constexpr (VMC == 2) asm volatile("s_waitcnt vmcnt(2)" ::: "memory");
  if constexpr (VMC == 0) asm volatile("s_waitcnt vmcnt(0)" ::: "memory");
  asm volatile("s_barrier" ::: "memory");
}

__global__ __launch_bounds__(512, 2) void gemm_kernel(
    const char* __restrict__ xq, const char* __restrict__ wq,
    const float* __restrict__ sx, const float* __restrict__ sw,
    const float* __restrict__ bias, float* __restrict__ out) {
  __shared__ char lds_c[131072];  // A: [0,64K) bufs 0/1; B: [64K,128K) bufs 0/1

  const int tid = threadIdx.x;
  const int lane = tid & 63;
  const int wave = tid >> 6;
  const int wm = wave >> 2;       // 0..1
  const int wn = wave & 3;        // 0..3
  const int lr = lane & 15;

  // T1: bijective XCD swizzle (1376 = 8*172)
  const int bid = blockIdx.x;
  const int sw_id = (bid & 7) * 172 + (bid >> 3);
  const int bm = sw_id / 43, bn = sw_id % 43;
  const int m0 = bm * 256, n0 = bn * 256;

  // staging source: thread t -> row tid>>3 (0..63), phys colbyte (tid&7)*16,
  // source colbyte = phys ^ ((row&7)<<4)   (inverse swizzle)
  const int srow = tid >> 3;
  const int srccb = ((tid & 7) << 4) ^ ((srow & 7) << 4);
  const char* gA0 = xq + (size_t)(m0 + srow) * K_DIM + srccb;
  const char* gB0 = wq + (size_t)(n0 + srow) * K_DIM + srccb;
  char* dA0 = lds_c + wave * 1024;            // wave-uniform; HW adds lane*16
  char* dB0 = lds_c + 65536 + wave * 1024;

  // read-side bases
  const int aRowOff = (wm * 128 + lr) * 128;
  const int bRowOff = (wn * 64 + lr) * 128;
  const int colswz = ((lane >> 4) << 4) ^ ((lr & 7) << 4);

  i32x4 acc[8][4] = {};

  // prologue: stage tile 0 (first-6, then a1,a3); keep 2 in flight
  GL(gA0, dA0);                    GL(gA0 + 2 * RROW, dA0 + 16384);
  GL(gB0, dB0);                    GL(gB0 + RROW, dB0 + 8192);
  GL(gB0 + 2 * RROW, dB0 + 16384); GL(gB0 + 3 * RROW, dB0 + 24576);
  GL(gA0 + RROW, dA0 + 8192);      GL(gA0 + 3 * RROW, dA0 + 24576);
  asm volatile("s_waitcnt vmcnt(2)" ::: "memory");
  asm volatile("s_barrier" ::: "memory");

  for (int t = 0; t < NT - 1; ++t) {
    const int buf = t & 1;
    const char* paRow = lds_c + buf * 32768 + aRowOff;
    const char* pbRow = lds_c + 65536 + buf * 32768 + bRowOff;
    const char* gAn = gA0 + (size_t)(t + 1) * 128;
    const char* gBn = gB0 + (size_t)(t + 1) * 128;
    char* dA = dA0 + (1 - buf) * 32768;
    char* dB = dB0 + (1 - buf) * 32768;
    i32x4 bf[4];
    phase<0, 0, true,  8, true >(paRow, pbRow, colswz, gAn, gBn, dA, dB, acc, bf);
    phase<1, 0, false,-1, false>(paRow, pbRow, colswz, gAn, gBn, dA, dB, acc, bf);
    phase<0, 1, true, -1, false>(paRow, pbRow, colswz, gAn, gBn, dA, dB, acc, bf);
    phase<1, 1, false, 2, false>(paRow, pbRow, colswz, gAn, gBn, dA, dB, acc, bf);
  }
  {  // tail tile: no staging; drain remaining a1,a3 at ph1-end
    const int buf = (NT - 1) & 1;
    const char* paRow = lds_c + buf * 32768 + aRowOff;
    const char* pbRow = lds_c + 65536 + buf * 32768 + bRowOff;
    i32x4 bf[4];
    phase<0, 0, true,  0, false>(paRow, pbRow, colswz, nullptr, nullptr, nullptr, nullptr, acc, bf);
    phase<1, 0, false,-1, false>(paRow, pbRow, colswz, nullptr, nullptr, nullptr, nullptr, acc, bf);
    phase<0, 1, true, -1, false>(paRow, pbRow, colswz, nullptr, nullptr, nullptr, nullptr, acc, bf);
    phase<1, 1, false,-1, false>(paRow, pbRow, colswz, nullptr, nullptr, nullptr, nullptr, acc, bf);
  }

  // epilogue: C/D layout col=lane&15, row=(lane>>4)*4+reg (dtype-independent, m121/m128)
  const int orow0 = m0 + wm * 128 + (lane >> 4) * 4;
  const int ocol0 = n0 + wn * 64 + lr;
  float bv[4], swv[4];
#pragma unroll
  for (int fc = 0; fc < 4; ++fc) {
    bv[fc] = bias[ocol0 + fc * 16];
    swv[fc] = sw[ocol0 + fc * 16];
  }
#pragma unroll
  for (int fr = 0; fr < 8; ++fr) {
#pragma unroll
    for (int j = 0; j < 4; ++j) {
      const int grow = orow0 + fr * 16 + j;
      const float s = sx[grow];
      float* op = out + (size_t)grow * N_DIM + ocol0;
#pragma unroll
      for (int fc = 0; fc < 4; ++fc)
        op[fc * 16] = (float)acc[fr][fc][j] * (s * swv[fc]) + bv[fc];
    }
  }
}

extern "C" void kernel_launch(void* const* d_in, const int* in_sizes, int n_in,
                              void* d_out, int out_size, void* d_ws, size_t ws_size,
                              hipStream_t stream) {
  (void)in_sizes; (void)n_in; (void)out_size; (void)ws_size;
  const float* x = (const float*)d_in[0];       // [4,2048,4096] f32
  const float* w = (const float*)d_in[1];       // [11008,4096] f32
  const float* bias = (const float*)d_in[2];    // [1,11008] f32
  float* out = (float*)d_out;                   // [8192,11008] f32

  char* ws = (char*)d_ws;
  float* sx = (float*)ws;                                   // 32 KiB
  float* sw = (float*)(ws + 32768);                         // 44 KiB
  char* xq8 = ws + 131072;                                  // 32 MiB int8
  char* wq8 = ws + 131072 + (size_t)M_DIM * K_DIM;          // 43 MiB int8

  quant_x_kernel<<<M_DIM, 256, 0, stream>>>(x, xq8, sx);
  quant_w_kernel<<<N_DIM, 256, 0, stream>>>(w, wq8, sw);
  gemm_kernel<<<dim3((M_DIM / 256) * (N_DIM / 256)), 512, 0, stream>>>(xq8, wq8, sx, sw, bias, out);
}

// Round 5
// 452.156 us; speedup vs baseline: 1.9058x; 1.0668x over previous
//
#include <hip/hip_runtime.h>
#include <hip/hip_bf16.h>

#define M_DIM 8192
#define N_DIM 11008
#define K_DIM 4096
#define NT 32                        // K-tiles of BK=128 (int8)
#define RROW ((size_t)64 * K_DIM)    // 64 rows of int8, in bytes

typedef __attribute__((ext_vector_type(4))) int i32x4;

// ---------------- per-token activation quant: n = rint(x/s), s = max(absmax,1e-5)/7 ----------------
__global__ void quant_x_kernel(const float* __restrict__ x,
                               char* __restrict__ xq, float* __restrict__ sx) {
  const int row = blockIdx.x;      // 8192
  const int t = threadIdx.x;       // 256
  const float4* xr4 = (const float4*)(x + (size_t)row * K_DIM);
  float4 v[4];
  float amax = 0.0f;
#pragma unroll
  for (int i = 0; i < 4; ++i) {
    v[i] = xr4[t + 256 * i];
    amax = fmaxf(amax, fmaxf(fmaxf(fabsf(v[i].x), fabsf(v[i].y)),
                             fmaxf(fabsf(v[i].z), fabsf(v[i].w))));
  }
#pragma unroll
  for (int off = 32; off > 0; off >>= 1)
    amax = fmaxf(amax, __shfl_xor(amax, off, 64));
  __shared__ float red[4];
  if ((t & 63) == 0) red[t >> 6] = amax;
  __syncthreads();
  amax = fmaxf(fmaxf(red[0], red[1]), fmaxf(red[2], red[3]));
  const float s = fmaxf(amax, 1e-5f) / 7.0f;   // matches reference bitwise
  if (t == 0) sx[row] = s;
  char q[16];
#pragma unroll
  for (int i = 0; i < 4; ++i) {
    q[i * 4 + 0] = (char)(int)rintf(v[i].x / s);  // RNE, exact ints in [-7,7]
    q[i * 4 + 1] = (char)(int)rintf(v[i].y / s);
    q[i * 4 + 2] = (char)(int)rintf(v[i].z / s);
    q[i * 4 + 3] = (char)(int)rintf(v[i].w / s);
  }
  *(int4*)(xq + (size_t)row * K_DIM + t * 16) = *(int4*)q;
}

// ---------------- per-output-channel weight quant: int8 / 127 ----------------
__global__ void quant_w_kernel(const float* __restrict__ w,
                               char* __restrict__ wq, float* __restrict__ sw) {
  const int row = blockIdx.x;      // 11008
  const int t = threadIdx.x;       // 256
  const float4* wr4 = (const float4*)(w + (size_t)row * K_DIM);
  float4 v[4];
  float amax = 0.0f;
#pragma unroll
  for (int i = 0; i < 4; ++i) {
    v[i] = wr4[t + 256 * i];
    amax = fmaxf(amax, fmaxf(fmaxf(fabsf(v[i].x), fabsf(v[i].y)),
                             fmaxf(fabsf(v[i].z), fabsf(v[i].w))));
  }
#pragma unroll
  for (int off = 32; off > 0; off >>= 1)
    amax = fmaxf(amax, __shfl_xor(amax, off, 64));
  __shared__ float red[4];
  if ((t & 63) == 0) red[t >> 6] = amax;
  __syncthreads();
  amax = fmaxf(fmaxf(red[0], red[1]), fmaxf(red[2], red[3]));
  const float s = fmaxf(amax, 1e-30f) / 127.0f;
  if (t == 0) sw[row] = s;
  char q[16];
#pragma unroll
  for (int i = 0; i < 4; ++i) {
    q[i * 4 + 0] = (char)(int)rintf(v[i].x / s);  // in [-127,127]
    q[i * 4 + 1] = (char)(int)rintf(v[i].y / s);
    q[i * 4 + 2] = (char)(int)rintf(v[i].z / s);
    q[i * 4 + 3] = (char)(int)rintf(v[i].w / s);
  }
  *(int4*)(wq + (size_t)row * K_DIM + t * 16) = *(int4*)q;
}

// ---------------- GEMM ----------------
// 256x256 tile, BK=128 int8 (128-B rows), 512 thr (8 waves 2x4), ring-2 LDS 128 KiB.
// ONE barrier per tile: stage t+1 at tile start (buffer free since the barrier),
// then ds_reads and MFMAs free-interleave across the whole tile (compiler's
// fine-grained lgkmcnt scheduling); __syncthreads() at tile end (its vmcnt(0)
// drain is free: staged loads had a whole tile to land).
// Swizzle (verified 0 conflicts): phys = row*128 + (col ^ ((row&7)<<4)),
// staged via inverse-swizzled global source (linear gload_lds dest).
#define GL(g, d)                                                             \
  __builtin_amdgcn_global_load_lds(                                          \
      (const __attribute__((address_space(1))) void*)(g),                    \
      (__attribute__((address_space(3))) void*)(d), 16, 0, 0)

template<bool STG>
__device__ __forceinline__ void tile_body(const char* paRow, const char* pbRow, int colswz,
    const char* gAn, const char* gBn, char* dA, char* dB, i32x4 (&acc)[8][4]) {
  if constexpr (STG) {
    GL(gAn, dA);                    GL(gAn + 2 * RROW, dA + 16384);
    GL(gBn, dB);                    GL(gBn + RROW, dB + 8192);
    GL(gBn + 2 * RROW, dB + 16384); GL(gBn + 3 * RROW, dB + 24576);
    GL(gAn + RROW, dA + 8192);      GL(gAn + 3 * RROW, dA + 24576);
  }
  const int c0 = colswz;
  const int c1 = colswz ^ 64;
  i32x4 a0[4], a1[4], a2[4], a3[4], b0[4], b1[4];
#pragma unroll
  for (int i = 0; i < 4; ++i) a0[i] = *(const i32x4*)(paRow + i * 2048 + c0);
#pragma unroll
  for (int i = 0; i < 4; ++i) b0[i] = *(const i32x4*)(pbRow + i * 2048 + c0);
#pragma unroll
  for (int i = 0; i < 4; ++i) a1[i] = *(const i32x4*)(paRow + 8192 + i * 2048 + c0);
#pragma unroll
  for (int m = 0; m < 4; ++m)
#pragma unroll
    for (int n = 0; n < 4; ++n)
      acc[m][n] = __builtin_amdgcn_mfma_i32_16x16x64_i8(a0[m], b0[n], acc[m][n], 0, 0, 0);
#pragma unroll
  for (int i = 0; i < 4; ++i) a2[i] = *(const i32x4*)(paRow + i * 2048 + c1);
#pragma unroll
  for (int i = 0; i < 4; ++i) b1[i] = *(const i32x4*)(pbRow + i * 2048 + c1);
#pragma unroll
  for (int m = 0; m < 4; ++m)
#pragma unroll
    for (int n = 0; n < 4; ++n)
      acc[4 + m][n] = __builtin_amdgcn_mfma_i32_16x16x64_i8(a1[m], b0[n], acc[4 + m][n], 0, 0, 0);
#pragma unroll
  for (int i = 0; i < 4; ++i) a3[i] = *(const i32x4*)(paRow + 8192 + i * 2048 + c1);
#pragma unroll
  for (int m = 0; m < 4; ++m)
#pragma unroll
    for (int n = 0; n < 4; ++n)
      acc[m][n] = __builtin_amdgcn_mfma_i32_16x16x64_i8(a2[m], b1[n], acc[m][n], 0, 0, 0);
#pragma unroll
  for (int m = 0; m < 4; ++m)
#pragma unroll
    for (int n = 0; n < 4; ++n)
      acc[4 + m][n] = __builtin_amdgcn_mfma_i32_16x16x64_i8(a3[m], b1[n], acc[4 + m][n], 0, 0, 0);
}

__global__ __launch_bounds__(512, 2) void gemm_kernel(
    const char* __restrict__ xq, const char* __restrict__ wq,
    const float* __restrict__ sx, const float* __restrict__ sw,
    const float* __restrict__ bias, float* __restrict__ out) {
  __shared__ char lds_c[131072];  // A: [0,64K) bufs 0/1; B: [64K,128K) bufs 0/1

  const int tid = threadIdx.x;
  const int lane = tid & 63;
  const int wave = tid >> 6;
  const int wm = wave >> 2;       // 0..1
  const int wn = wave & 3;        // 0..3
  const int lr = lane & 15;

  // T1: bijective XCD swizzle (1376 = 8*172)
  const int bid = blockIdx.x;
  const int sw_id = (bid & 7) * 172 + (bid >> 3);
  const int bm = sw_id / 43, bn = sw_id % 43;
  const int m0 = bm * 256, n0 = bn * 256;

  // staging source: thread t -> row tid>>3 (0..63), phys colbyte (tid&7)*16,
  // source colbyte = phys ^ ((row&7)<<4)   (inverse swizzle)
  const int srow = tid >> 3;
  const int srccb = ((tid & 7) << 4) ^ ((srow & 7) << 4);
  const char* gA0 = xq + (size_t)(m0 + srow) * K_DIM + srccb;
  const char* gB0 = wq + (size_t)(n0 + srow) * K_DIM + srccb;
  char* dA0 = lds_c + wave * 1024;            // wave-uniform; HW adds lane*16
  char* dB0 = lds_c + 65536 + wave * 1024;

  // read-side bases
  const int aRowOff = (wm * 128 + lr) * 128;
  const int bRowOff = (wn * 64 + lr) * 128;
  const int colswz = ((lane >> 4) << 4) ^ ((lr & 7) << 4);

  i32x4 acc[8][4] = {};

  // prologue: stage tile 0 into buf 0
  GL(gA0, dA0);                    GL(gA0 + 2 * RROW, dA0 + 16384);
  GL(gB0, dB0);                    GL(gB0 + RROW, dB0 + 8192);
  GL(gB0 + 2 * RROW, dB0 + 16384); GL(gB0 + 3 * RROW, dB0 + 24576);
  GL(gA0 + RROW, dA0 + 8192);      GL(gA0 + 3 * RROW, dA0 + 24576);
  __syncthreads();

  for (int t = 0; t < NT - 1; ++t) {
    const int buf = t & 1;
    tile_body<true>(lds_c + buf * 32768 + aRowOff,
                    lds_c + 65536 + buf * 32768 + bRowOff, colswz,
                    gA0 + (size_t)(t + 1) * 128, gB0 + (size_t)(t + 1) * 128,
                    dA0 + (1 - buf) * 32768, dB0 + (1 - buf) * 32768, acc);
    __syncthreads();
  }
  tile_body<false>(lds_c + ((NT - 1) & 1) * 32768 + aRowOff,
                   lds_c + 65536 + ((NT - 1) & 1) * 32768 + bRowOff, colswz,
                   nullptr, nullptr, nullptr, nullptr, acc);

  // epilogue: C/D layout col=lane&15, row=(lane>>4)*4+reg (dtype-independent, m121/m128)
  const int orow0 = m0 + wm * 128 + (lane >> 4) * 4;
  const int ocol0 = n0 + wn * 64 + lr;
  float bv[4], swv[4];
#pragma unroll
  for (int fc = 0; fc < 4; ++fc) {
    bv[fc] = bias[ocol0 + fc * 16];
    swv[fc] = sw[ocol0 + fc * 16];
  }
#pragma unroll
  for (int fr = 0; fr < 8; ++fr) {
#pragma unroll
    for (int j = 0; j < 4; ++j) {
      const int grow = orow0 + fr * 16 + j;
      const float s = sx[grow];
      float* op = out + (size_t)grow * N_DIM + ocol0;
#pragma unroll
      for (int fc = 0; fc < 4; ++fc)
        op[fc * 16] = (float)acc[fr][fc][j] * (s * swv[fc]) + bv[fc];
    }
  }
}

extern "C" void kernel_launch(void* const* d_in, const int* in_sizes, int n_in,
                              void* d_out, int out_size, void* d_ws, size_t ws_size,
                              hipStream_t stream) {
  (void)in_sizes; (void)n_in; (void)out_size; (void)ws_size;
  const float* x = (const float*)d_in[0];       // [4,2048,4096] f32
  const float* w = (const float*)d_in[1];       // [11008,4096] f32
  const float* bias = (const float*)d_in[2];    // [1,11008] f32
  float* out = (float*)d_out;                   // [8192,11008] f32

  char* ws = (char*)d_ws;
  float* sx = (float*)ws;                                   // 32 KiB
  float* sw = (float*)(ws + 32768);                         // 44 KiB
  char* xq8 = ws + 131072;                                  // 32 MiB int8
  char* wq8 = ws + 131072 + (size_t)M_DIM * K_DIM;          // 43 MiB int8

  quant_x_kernel<<<M_DIM, 256, 0, stream>>>(x, xq8, sx);
  quant_w_kernel<<<N_DIM, 256, 0, stream>>>(w, wq8, sw);
  gemm_kernel<<<dim3((M_DIM / 256) * (N_DIM / 256)), 512, 0, stream>>>(xq8, wq8, sx, sw, bias, out);
}

// Round 6
// 436.262 us; speedup vs baseline: 1.9752x; 1.0364x over previous
//
#include <hip/hip_runtime.h>
#include <hip/hip_bf16.h>

#define M_DIM 8192
#define N_DIM 11008
#define K_DIM 4096
#define NT 32                        // K-tiles of BK=128 (int8)
#define RROW ((size_t)64 * K_DIM)    // 64 rows of int8, in bytes

typedef __attribute__((ext_vector_type(4))) int i32x4;

// ---------------- per-token activation quant: n = rint(x/s), s = max(absmax,1e-5)/7 ----------------
__global__ void quant_x_kernel(const float* __restrict__ x,
                               char* __restrict__ xq, float* __restrict__ sx) {
  const int row = blockIdx.x;      // 8192
  const int t = threadIdx.x;       // 256
  const float4* xr4 = (const float4*)(x + (size_t)row * K_DIM);
  float4 v[4];
  float amax = 0.0f;
#pragma unroll
  for (int i = 0; i < 4; ++i) {
    v[i] = xr4[t + 256 * i];
    amax = fmaxf(amax, fmaxf(fmaxf(fabsf(v[i].x), fabsf(v[i].y)),
                             fmaxf(fabsf(v[i].z), fabsf(v[i].w))));
  }
#pragma unroll
  for (int off = 32; off > 0; off >>= 1)
    amax = fmaxf(amax, __shfl_xor(amax, off, 64));
  __shared__ float red[4];
  if ((t & 63) == 0) red[t >> 6] = amax;
  __syncthreads();
  amax = fmaxf(fmaxf(red[0], red[1]), fmaxf(red[2], red[3]));
  const float s = fmaxf(amax, 1e-5f) / 7.0f;   // matches reference bitwise
  if (t == 0) sx[row] = s;
  char q[16];
#pragma unroll
  for (int i = 0; i < 4; ++i) {
    q[i * 4 + 0] = (char)(int)rintf(v[i].x / s);  // RNE, exact ints in [-7,7]
    q[i * 4 + 1] = (char)(int)rintf(v[i].y / s);
    q[i * 4 + 2] = (char)(int)rintf(v[i].z / s);
    q[i * 4 + 3] = (char)(int)rintf(v[i].w / s);
  }
  *(int4*)(xq + (size_t)row * K_DIM + t * 16) = *(int4*)q;
}

// ---------------- per-output-channel weight quant: int8 / 127 ----------------
__global__ void quant_w_kernel(const float* __restrict__ w,
                               char* __restrict__ wq, float* __restrict__ sw) {
  const int row = blockIdx.x;      // 11008
  const int t = threadIdx.x;       // 256
  const float4* wr4 = (const float4*)(w + (size_t)row * K_DIM);
  float4 v[4];
  float amax = 0.0f;
#pragma unroll
  for (int i = 0; i < 4; ++i) {
    v[i] = wr4[t + 256 * i];
    amax = fmaxf(amax, fmaxf(fmaxf(fabsf(v[i].x), fabsf(v[i].y)),
                             fmaxf(fabsf(v[i].z), fabsf(v[i].w))));
  }
#pragma unroll
  for (int off = 32; off > 0; off >>= 1)
    amax = fmaxf(amax, __shfl_xor(amax, off, 64));
  __shared__ float red[4];
  if ((t & 63) == 0) red[t >> 6] = amax;
  __syncthreads();
  amax = fmaxf(fmaxf(red[0], red[1]), fmaxf(red[2], red[3]));
  const float s = fmaxf(amax, 1e-30f) / 127.0f;
  if (t == 0) sw[row] = s;
  char q[16];
#pragma unroll
  for (int i = 0; i < 4; ++i) {
    q[i * 4 + 0] = (char)(int)rintf(v[i].x / s);  // in [-127,127]
    q[i * 4 + 1] = (char)(int)rintf(v[i].y / s);
    q[i * 4 + 2] = (char)(int)rintf(v[i].z / s);
    q[i * 4 + 3] = (char)(int)rintf(v[i].w / s);
  }
  *(int4*)(wq + (size_t)row * K_DIM + t * 16) = *(int4*)q;
}

// ---------------- GEMM ----------------
// 256x256 tile, BK=128 int8, 512 thr (8 waves 2x4), ring-2 LDS 128 KiB.
// One __syncthreads per tile. Tile body = 4 segments fenced by sched_barrier(0):
// each segment {ds_reads for NEXT mfma group || 16 MFMA of CURRENT group}, so
// reads lead their use by one full MFMA cluster and LDS/MFMA pipes overlap.
// The last MFMA group of a tile executes after the next tile's barrier (operands
// carried in registers). Swizzle (verified 0 conflicts): phys = row*128 +
// (col ^ ((row&7)<<4)), staged via inverse-swizzled global source.
#define GL(g, d)                                                             \
  __builtin_amdgcn_global_load_lds(                                          \
      (const __attribute__((address_space(1))) void*)(g),                    \
      (__attribute__((address_space(3))) void*)(d), 16, 0, 0)

template<int KK>
__device__ __forceinline__ void read_g1(const char* paRow, const char* pbRow, int colswz,
                                        i32x4 (&a)[4], i32x4 (&b)[4]) {
  const int c = colswz ^ (KK * 64);
#pragma unroll
  for (int i = 0; i < 4; ++i) a[i] = *(const i32x4*)(paRow + i * 2048 + c);
#pragma unroll
  for (int i = 0; i < 4; ++i) b[i] = *(const i32x4*)(pbRow + i * 2048 + c);
}
template<int KK>
__device__ __forceinline__ void read_g2(const char* paRow, int colswz, i32x4 (&a)[4]) {
  const int c = colswz ^ (KK * 64);
#pragma unroll
  for (int i = 0; i < 4; ++i) a[i] = *(const i32x4*)(paRow + 8192 + i * 2048 + c);
}
template<int OFF>
__device__ __forceinline__ void mfma16(const i32x4 (&a)[4], const i32x4 (&b)[4],
                                       i32x4 (&acc)[8][4]) {
#pragma unroll
  for (int m = 0; m < 4; ++m)
#pragma unroll
    for (int n = 0; n < 4; ++n)
      acc[OFF + m][n] = __builtin_amdgcn_mfma_i32_16x16x64_i8(a[m], b[n], acc[OFF + m][n], 0, 0, 0);
}

template<bool FIRST, bool STG>
__device__ __forceinline__ void tile(const char* paRow, const char* pbRow, int colswz,
    const char* gAn, const char* gBn, char* dA, char* dB,
    i32x4 (&acc)[8][4], i32x4 (&bP)[4], i32x4 (&a2P)[4]) {
  __syncthreads();  // tile's buffer staged & other buffer's readers done
  if constexpr (STG) {
    GL(gAn, dA);                    GL(gAn + 2 * RROW, dA + 16384);
    GL(gBn, dB);                    GL(gBn + RROW, dB + 8192);
    GL(gBn + 2 * RROW, dB + 16384); GL(gBn + 3 * RROW, dB + 24576);
    GL(gAn + RROW, dA + 8192);      GL(gAn + 3 * RROW, dA + 24576);
  }
  i32x4 a10[4], b0[4], a20[4], a11[4], b1[4], a21[4];
  // seg1: reads g1(k0) || MFMA g2(prev tile, k1)
  read_g1<0>(paRow, pbRow, colswz, a10, b0);
  if constexpr (!FIRST) mfma16<4>(a2P, bP, acc);
  __builtin_amdgcn_sched_barrier(0);
  // seg2: reads g2(k0) || MFMA g1(k0)
  read_g2<0>(paRow, colswz, a20);
  mfma16<0>(a10, b0, acc);
  __builtin_amdgcn_sched_barrier(0);
  // seg3: reads g1(k1) || MFMA g2(k0)
  read_g1<1>(paRow, pbRow, colswz, a11, b1);
  mfma16<4>(a20, b0, acc);
  __builtin_amdgcn_sched_barrier(0);
  // seg4: reads g2(k1) || MFMA g1(k1); g2(k1) becomes next tile's pending
  read_g2<1>(paRow, colswz, a21);
  mfma16<0>(a11, b1, acc);
#pragma unroll
  for (int i = 0; i < 4; ++i) { bP[i] = b1[i]; a2P[i] = a21[i]; }
}

__global__ __launch_bounds__(512, 2) void gemm_kernel(
    const char* __restrict__ xq, const char* __restrict__ wq,
    const float* __restrict__ sx, const float* __restrict__ sw,
    const float* __restrict__ bias, float* __restrict__ out) {
  __shared__ char lds_c[131072];  // A: [0,64K) bufs 0/1; B: [64K,128K) bufs 0/1

  const int tid = threadIdx.x;
  const int lane = tid & 63;
  const int wave = tid >> 6;
  const int wm = wave >> 2;       // 0..1
  const int wn = wave & 3;        // 0..3
  const int lr = lane & 15;

  // T1: bijective XCD swizzle (1376 = 8*172)
  const int bid = blockIdx.x;
  const int sw_id = (bid & 7) * 172 + (bid >> 3);
  const int bm = sw_id / 43, bn = sw_id % 43;
  const int m0 = bm * 256, n0 = bn * 256;

  // staging source: thread t -> row tid>>3 (0..63), phys colbyte (tid&7)*16,
  // source colbyte = phys ^ ((row&7)<<4)   (inverse swizzle)
  const int srow = tid >> 3;
  const int srccb = ((tid & 7) << 4) ^ ((srow & 7) << 4);
  const char* gA0 = xq + (size_t)(m0 + srow) * K_DIM + srccb;
  const char* gB0 = wq + (size_t)(n0 + srow) * K_DIM + srccb;
  char* dA0 = lds_c + wave * 1024;            // wave-uniform; HW adds lane*16
  char* dB0 = lds_c + 65536 + wave * 1024;

  // read-side bases
  const int aRowOff = (wm * 128 + lr) * 128;
  const int bRowOff = (wn * 64 + lr) * 128;
  const int colswz = ((lane >> 4) << 4) ^ ((lr & 7) << 4);

  i32x4 acc[8][4] = {};
  i32x4 bP[4], a2P[4];

  // prologue: stage tile 0 into buf 0 (drained by the first tile's barrier)
  GL(gA0, dA0);                    GL(gA0 + 2 * RROW, dA0 + 16384);
  GL(gB0, dB0);                    GL(gB0 + RROW, dB0 + 8192);
  GL(gB0 + 2 * RROW, dB0 + 16384); GL(gB0 + 3 * RROW, dB0 + 24576);
  GL(gA0 + RROW, dA0 + 8192);      GL(gA0 + 3 * RROW, dA0 + 24576);

  tile<true, true>(lds_c + aRowOff, lds_c + 65536 + bRowOff, colswz,
                   gA0 + 128, gB0 + 128, dA0 + 32768, dB0 + 32768, acc, bP, a2P);
  for (int t = 1; t < NT - 1; ++t) {
    const int buf = t & 1;
    tile<false, true>(lds_c + buf * 32768 + aRowOff,
                      lds_c + 65536 + buf * 32768 + bRowOff, colswz,
                      gA0 + (size_t)(t + 1) * 128, gB0 + (size_t)(t + 1) * 128,
                      dA0 + (1 - buf) * 32768, dB0 + (1 - buf) * 32768, acc, bP, a2P);
  }
  tile<false, false>(lds_c + ((NT - 1) & 1) * 32768 + aRowOff,
                     lds_c + 65536 + ((NT - 1) & 1) * 32768 + bRowOff, colswz,
                     nullptr, nullptr, nullptr, nullptr, acc, bP, a2P);
  mfma16<4>(a2P, bP, acc);  // final pending group

  // epilogue: C/D layout col=lane&15, row=(lane>>4)*4+reg (dtype-independent, m121/m128)
  const int orow0 = m0 + wm * 128 + (lane >> 4) * 4;
  const int ocol0 = n0 + wn * 64 + lr;
  float bv[4], swv[4];
#pragma unroll
  for (int fc = 0; fc < 4; ++fc) {
    bv[fc] = bias[ocol0 + fc * 16];
    swv[fc] = sw[ocol0 + fc * 16];
  }
#pragma unroll
  for (int fr = 0; fr < 8; ++fr) {
#pragma unroll
    for (int j = 0; j < 4; ++j) {
      const int grow = orow0 + fr * 16 + j;
      const float s = sx[grow];
      float* op = out + (size_t)grow * N_DIM + ocol0;
#pragma unroll
      for (int fc = 0; fc < 4; ++fc)
        op[fc * 16] = (float)acc[fr][fc][j] * (s * swv[fc]) + bv[fc];
    }
  }
}

extern "C" void kernel_launch(void* const* d_in, const int* in_sizes, int n_in,
                              void* d_out, int out_size, void* d_ws, size_t ws_size,
                              hipStream_t stream) {
  (void)in_sizes; (void)n_in; (void)out_size; (void)ws_size;
  const float* x = (const float*)d_in[0];       // [4,2048,4096] f32
  const float* w = (const float*)d_in[1];       // [11008,4096] f32
  const float* bias = (const float*)d_in[2];    // [1,11008] f32
  float* out = (float*)d_out;                   // [8192,11008] f32

  char* ws = (char*)d_ws;
  float* sx = (float*)ws;                                   // 32 KiB
  float* sw = (float*)(ws + 32768);                         // 44 KiB
  char* xq8 = ws + 131072;                                  // 32 MiB int8
  char* wq8 = ws + 131072 + (size_t)M_DIM * K_DIM;          // 43 MiB int8

  quant_x_kernel<<<M_DIM, 256, 0, stream>>>(x, xq8, sx);
  quant_w_kernel<<<N_DIM, 256, 0, stream>>>(w, wq8, sw);
  gemm_kernel<<<dim3((M_DIM / 256) * (N_DIM / 256)), 512, 0, stream>>>(xq8, wq8, sx, sw, bias, out);
}